// Round 10
// baseline (244.440 us; speedup 1.0000x reference)
//
#include <hip/hip_runtime.h>
#include <cstdint>

#define K_DIM 3072
#define B_DIM 8192
#define ROW_B 3072    /* bytes per i8 row */
#define ROW_U 768     /* u32 per i8 row */
#define BMA   256     /* A-rows per tile */
#define BNB   128     /* B-cols per tile */
#define NTB   64      /* 8192/128 col tiles */
#define NKT   48      /* K_DIM/64 K-tiles */
#define ABYTES 16384  /* A half of one LDS buffer (256 rows x 64 B) */
#define BUFSZ  24576  /* one LDS buffer: A 16KB + B 8KB */

typedef __attribute__((ext_vector_type(4))) float f32x4;
typedef __attribute__((ext_vector_type(4))) int   i32x4;

#define QS     16.0f          /* quant scale: q = rn(x*16), exact mul */
#define INV_S2 0.00390625f    /* 1/256 */

__device__ __forceinline__ int q8(float f) {
    int q = __float2int_rn(f * QS);
    return max(-127, min(127, q));
}
__device__ __forceinline__ unsigned pack4(float a, float b, float c, float d) {
    return (unsigned)(q8(a) & 0xFF)
         | ((unsigned)(q8(b) & 0xFF) << 8)
         | ((unsigned)(q8(c) & 0xFF) << 16)
         | ((unsigned)(q8(d) & 0xFF) << 24);
}

// ---------- kernel 1: fused x_t write + i8 quantize (row-major) + row |x|^2 ----------
__global__ __launch_bounds__(384) void prep_kernel(const float* __restrict__ x,
                                                   const float* __restrict__ nz,
                                                   const float* __restrict__ logvar,
                                                   float* __restrict__ xt,     // may be null
                                                   unsigned int* __restrict__ xb,
                                                   float* __restrict__ xn,
                                                   float* __restrict__ se)
{
    const int row = blockIdx.x;
    const int tid = threadIdx.x;            // 384 threads: 8 consecutive floats each
    const float4* xr = (const float4*)(x + (size_t)row * K_DIM);
    float4 v0 = xr[2 * tid];
    float4 v1 = xr[2 * tid + 1];
    float s = v0.x * v0.x + v0.y * v0.y + v0.z * v0.z + v0.w * v0.w
            + v1.x * v1.x + v1.y * v1.y + v1.z * v1.z + v1.w * v1.w;

    if (xt) {   // fused x_t = x + exp(0.5*logvar)*noise
        const float4* nr = (const float4*)(nz + (size_t)row * K_DIM);
        float4 n0 = nr[2 * tid], n1 = nr[2 * tid + 1];
        const float sc = __expf(0.5f * logvar[0]);
        float4 o0, o1;
        o0.x = fmaf(sc, n0.x, v0.x); o0.y = fmaf(sc, n0.y, v0.y);
        o0.z = fmaf(sc, n0.z, v0.z); o0.w = fmaf(sc, n0.w, v0.w);
        o1.x = fmaf(sc, n1.x, v1.x); o1.y = fmaf(sc, n1.y, v1.y);
        o1.z = fmaf(sc, n1.z, v1.z); o1.w = fmaf(sc, n1.w, v1.w);
        float4* tr = (float4*)(xt + (size_t)row * K_DIM);
        tr[2 * tid] = o0;
        tr[2 * tid + 1] = o1;
    }

    unsigned int* dst = xb + (size_t)row * ROW_U + tid * 2;
    dst[0] = pack4(v0.x, v0.y, v0.z, v0.w);
    dst[1] = pack4(v1.x, v1.y, v1.z, v1.w);

#pragma unroll
    for (int d = 32; d > 0; d >>= 1) s += __shfl_down(s, d);
    __shared__ float red[6];
    if ((tid & 63) == 0) red[tid >> 6] = s;
    __syncthreads();
    if (tid == 0) {
        float t = 0.f;
#pragma unroll
        for (int i = 0; i < 6; ++i) t += red[i];
        xn[row] = t;
        se[row] = 0.f;
    }
}

// ---------- kernel 2: 256x128 triangular i8 Gram, 4 waves of 128x64,
//            R6-style simple body + 3-buf counted-vmcnt, 2 blocks/CU ----------
__global__ __launch_bounds__(256, 2) void gram_lse_kernel(const unsigned int* __restrict__ xb,
                                                          const float* __restrict__ xn,
                                                          const float* __restrict__ logvar,
                                                          float* __restrict__ se)
{
    __shared__ __align__(1024) unsigned char lds[3][BUFSZ];   // 72 KiB

    // XCD swizzle (bijective: 1056 = 8*132) then triangular decode
    const int orig = blockIdx.x;
    int rem = (orig & 7) * 132 + (orig >> 3);
    int a = 0;
    while (rem >= NTB - 2 * a) { rem -= NTB - 2 * a; ++a; }
    const int v = 2 * a + rem;              // a in [0,32), v in [2a,64)

    const int tid  = threadIdx.x;           // 256
    const int lane = tid & 63;
    const int wave = tid >> 6;              // 4 waves: 2(M) x 2(N)
    const int wr = wave >> 1, wc = wave & 1;
    const int fc = lane >> 4;               // 16B chunk group 0..3

    const size_t rowA0 = (size_t)a * BMA;
    const size_t rowB0 = (size_t)v * BNB;
    const unsigned char* xb8 = (const unsigned char*)xb;

    // staging: 6 slots/thread/K-tile (4 A + 2 B), 16 B each.
    // element e -> row r=e>>2, chunk c=e&3 (rows are 64 B = 4 chunks).
    // source chunk PRE-SWIZZLED (c ^ (r>>1)&3); LDS dest linear (rule #21).
    unsigned int srcOff[6];
    int dstOff[6];
#pragma unroll
    for (int l = 0; l < 6; ++l) {
        const int e = (l < 4) ? (l * 256 + tid) : ((l - 4) * 256 + tid);
        const int r = e >> 2, c = e & 3;
        const int csw = c ^ ((r >> 1) & 3);
        const size_t rb = ((l < 4) ? rowA0 : rowB0) + (size_t)r;
        srcOff[l] = (unsigned int)(rb * ROW_B + (size_t)csw * 16);
        dstOff[l] = ((l < 4) ? 0 : ABYTES) + e * 16;
    }

    // fragment LDS offsets (iter-invariant, swizzled read; zero-conflict per R3)
    int aOff[8], bOff[4];
#pragma unroll
    for (int mi = 0; mi < 8; ++mi) {
        const int r = wr * 128 + mi * 16 + (lane & 15);
        aOff[mi] = r * 64 + (fc ^ ((r >> 1) & 3)) * 16;
    }
#pragma unroll
    for (int ni = 0; ni < 4; ++ni) {
        const int r = wc * 64 + ni * 16 + (lane & 15);
        bOff[ni] = ABYTES + r * 64 + (fc ^ ((r >> 1) & 3)) * 16;
    }

    i32x4 acc[8][4];
#pragma unroll
    for (int i = 0; i < 8; ++i)
#pragma unroll
        for (int j = 0; j < 4; ++j) acc[i][j] = (i32x4){0, 0, 0, 0};

#define GLOAD(l, t, buf)                                                          \
    __builtin_amdgcn_global_load_lds(                                             \
        (const __attribute__((address_space(1))) void*)(xb8 + srcOff[l] + (unsigned)(t) * 64u), \
        (__attribute__((address_space(3))) void*)(&lds[buf][0] + dstOff[l]), 16, 0, 0)

    // prologue: stage tiles 0,1 into buffers 0,1
#pragma unroll
    for (int l = 0; l < 6; ++l) GLOAD(l, 0, 0);
#pragma unroll
    for (int l = 0; l < 6; ++l) GLOAD(l, 1, 1);
    asm volatile("s_waitcnt vmcnt(6)" ::: "memory");   // tile 0 landed; tile 1 in flight
    asm volatile("s_barrier" ::: "memory");

    for (int t = 0; t < NKT; ++t) {
        const unsigned char* cur = &lds[t % 3][0];

        // 1. prefetch tile t+2 into buf (t+2)%3 (its readers drained at end of t-1)
        if (t + 2 < NKT) {
            const int nb = (t + 2) % 3;
#pragma unroll
            for (int l = 0; l < 6; ++l) GLOAD(l, t + 2, nb);
        }

        // 2. read THIS tile's fragments and MFMA (compiler interleaves via
        //    fine-grained lgkmcnt -- the proven m97/R6 body)
        i32x4 aF[8], bF[4];
#pragma unroll
        for (int ni = 0; ni < 4; ++ni) bF[ni] = *(const i32x4*)(cur + bOff[ni]);
#pragma unroll
        for (int mi = 0; mi < 8; ++mi) aF[mi] = *(const i32x4*)(cur + aOff[mi]);

        __builtin_amdgcn_s_setprio(1);
#pragma unroll
        for (int mi = 0; mi < 8; ++mi)
#pragma unroll
            for (int ni = 0; ni < 4; ++ni)
                acc[mi][ni] = __builtin_amdgcn_mfma_i32_16x16x64_i8(
                    aF[mi], bF[ni], acc[mi][ni], 0, 0, 0);
        __builtin_amdgcn_s_setprio(0);

        // 3. WAR safety for my ds_reads, counted fence for tile t+1, barrier
        asm volatile("s_waitcnt lgkmcnt(0)" ::: "memory");
        if (t + 2 < NKT)
            asm volatile("s_waitcnt vmcnt(6)" ::: "memory");   // t+1 landed; t+2 in flight
        else
            asm volatile("s_waitcnt vmcnt(0)" ::: "memory");
        asm volatile("s_barrier" ::: "memory");
    }
#undef GLOAD

    // ---- fused epilogue: exp terms + row/col partial sums ----
    const float lv  = logvar[0];
    const float var = __expf(lv) + 1e-10f;
    const float cc  = 0.5f / var;

    const int u = 2 * a + wr;               // this wave's 128-row cell index
    if (u > v) return;                      // below-diagonal half of a v==2a tile

    const int colBase = (int)rowB0 + wc * 64 + (lane & 15);
    const int rowBase = (int)rowA0 + wr * 128 + (lane >> 4) * 4;

    // row sums -> se[i]  (i==j override handles diagonal exactly)
#pragma unroll
    for (int mi = 0; mi < 8; ++mi) {
#pragma unroll
        for (int rg = 0; rg < 4; ++rg) {
            const int i = rowBase + mi * 16 + rg;
            const float xni = xn[i];
            float rs = 0.f;
#pragma unroll
            for (int ni = 0; ni < 4; ++ni) {
                const int j = colBase + ni * 16;
                const float g = (float)acc[mi][ni][rg] * INV_S2;
                const float dist = xni + xn[j] - 2.f * g;
                rs += (i == j) ? 1.0f : __expf(-cc * fmaxf(dist, 0.f));
            }
#pragma unroll
            for (int d = 1; d < 16; d <<= 1) rs += __shfl_xor(rs, d);
            if ((lane & 15) == 0) atomicAdd(&se[i], rs);
        }
    }

    // col-mirror sums -> se[j], strictly-off-diagonal cells only (i < j always)
    if (u < v) {
#pragma unroll
        for (int ni = 0; ni < 4; ++ni) {
            const int j = colBase + ni * 16;
            const float xnj = xn[j];
            float cs = 0.f;
#pragma unroll
            for (int mi = 0; mi < 8; ++mi)
#pragma unroll
                for (int rg = 0; rg < 4; ++rg) {
                    const int i = rowBase + mi * 16 + rg;
                    const float g = (float)acc[mi][ni][rg] * INV_S2;
                    cs += __expf(-cc * fmaxf(xn[i] + xnj - 2.f * g, 0.f));
                }
#pragma unroll
            for (int d = 16; d < 64; d <<= 1) cs += __shfl_xor(cs, d);
            if ((lane >> 4) == 0) atomicAdd(&se[j], cs);
        }
    }
}

// ---------- kernel 3: KL scalar ----------
__global__ __launch_bounds__(256) void kl_kernel(const float* __restrict__ se,
                                                 float* __restrict__ out)
{
    const int tid = threadIdx.x;
    float s = 0.f;
    for (int i = tid; i < B_DIM; i += 256) s += logf(se[i]);
#pragma unroll
    for (int d = 32; d > 0; d >>= 1) s += __shfl_down(s, d);
    __shared__ float red[4];
    if ((tid & 63) == 0) red[tid >> 6] = s;
    __syncthreads();
    if (tid == 0) {
        const float dc = -(red[0] + red[1] + red[2] + red[3]) / (float)B_DIM;
        out[0] = (logf((float)B_DIM) + dc) / logf(2.f);
    }
}

// ---------- kernel 4 (fallback path only): x_t elementwise ----------
__global__ __launch_bounds__(256) void xt_kernel(const float4* __restrict__ x,
                                                 const float4* __restrict__ nz,
                                                 const float* __restrict__ logvar,
                                                 float4* __restrict__ out, int n4)
{
    const float sc = expf(0.5f * logvar[0]);
    for (int i = blockIdx.x * blockDim.x + threadIdx.x; i < n4;
         i += gridDim.x * blockDim.x) {
        float4 va = x[i], vb = nz[i];
        float4 o;
        o.x = fmaf(sc, vb.x, va.x);
        o.y = fmaf(sc, vb.y, va.y);
        o.z = fmaf(sc, vb.z, va.z);
        o.w = fmaf(sc, vb.w, va.w);
        out[i] = o;
    }
}

extern "C" void kernel_launch(void* const* d_in, const int* in_sizes, int n_in,
                              void* d_out, int out_size, void* d_ws, size_t ws_size,
                              hipStream_t stream)
{
    const float* x      = (const float*)d_in[0];
    const float* noise  = (const float*)d_in[1];
    const float* logvar = (const float*)d_in[2];
    float* out = (float*)d_out;

    const size_t NEL      = (size_t)B_DIM * K_DIM;      // 25165824
    const size_t XB_BYTES = (size_t)B_DIM * ROW_B;      // 25165824 B
    const int    NTILES   = 1056;                       // sum_{a<32} (64-2a)

    const bool use_ws = ws_size >= XB_BYTES + 2 * (size_t)B_DIM * sizeof(float) + 256;

    if (use_ws) {
        // xb/xn/se live in d_ws; x_t written directly by fused prep
        unsigned int* xb = (unsigned int*)d_ws;
        float* xn = (float*)((char*)d_ws + XB_BYTES);
        float* se = xn + B_DIM;

        prep_kernel<<<B_DIM, 384, 0, stream>>>(x, noise, logvar, out, xb, xn, se);
        gram_lse_kernel<<<NTILES, 256, 0, stream>>>(xb, xn, logvar, se);
        kl_kernel<<<1, 256, 0, stream>>>(se, out + NEL);
    } else {
        // fallback: scratch carved from d_out, x_t written last
        unsigned int* xb = (unsigned int*)d_out;
        float* xn = (float*)((char*)d_out + (32u << 20));
        float* se = xn + B_DIM;

        prep_kernel<<<B_DIM, 384, 0, stream>>>(x, noise, logvar, nullptr, xb, xn, se);
        gram_lse_kernel<<<NTILES, 256, 0, stream>>>(xb, xn, logvar, se);
        kl_kernel<<<1, 256, 0, stream>>>(se, out + NEL);
        xt_kernel<<<2048, 256, 0, stream>>>((const float4*)x, (const float4*)noise,
                                            logvar, (float4*)out, (int)(NEL / 4));
    }
}

// Round 11
// 210.705 us; speedup vs baseline: 1.1601x; 1.1601x over previous
//
#include <hip/hip_runtime.h>
#include <cstdint>

#define K_DIM 3072
#define B_DIM 8192
#define ROW_B 3072    /* bytes per i8 row */
#define ROW_U 768     /* u32 per i8 row */
#define BMA   256     /* A-rows per tile */
#define BNB   128     /* B-cols per tile */
#define NTB   64      /* 8192/128 col tiles */
#define NKT   48      /* K_DIM/64 K-tiles */

typedef __attribute__((ext_vector_type(4))) float        f32x4;
typedef __attribute__((ext_vector_type(4))) int          i32x4;

#define QS     16.0f          /* quant scale: q = rn(x*16), exact mul */
#define INV_S2 0.00390625f    /* 1/256 */

__device__ __forceinline__ int q8(float f) {
    int q = __float2int_rn(f * QS);
    return max(-127, min(127, q));
}
__device__ __forceinline__ unsigned pack4(float a, float b, float c, float d) {
    return (unsigned)(q8(a) & 0xFF)
         | ((unsigned)(q8(b) & 0xFF) << 8)
         | ((unsigned)(q8(c) & 0xFF) << 16)
         | ((unsigned)(q8(d) & 0xFF) << 24);
}

// ---------- kernel 1: fused x_t write + i8 quantize (row-major) + row |x|^2 ----------
__global__ __launch_bounds__(384) void prep_kernel(const float* __restrict__ x,
                                                   const float* __restrict__ nz,
                                                   const float* __restrict__ logvar,
                                                   float* __restrict__ xt,     // may be null
                                                   unsigned int* __restrict__ xb,
                                                   float* __restrict__ xn,
                                                   float* __restrict__ se)
{
    const int row = blockIdx.x;
    const int tid = threadIdx.x;            // 384 threads: 8 consecutive floats each
    const float4* xr = (const float4*)(x + (size_t)row * K_DIM);
    float4 v0 = xr[2 * tid];
    float4 v1 = xr[2 * tid + 1];
    float s = v0.x * v0.x + v0.y * v0.y + v0.z * v0.z + v0.w * v0.w
            + v1.x * v1.x + v1.y * v1.y + v1.z * v1.z + v1.w * v1.w;

    if (xt) {   // fused x_t = x + exp(0.5*logvar)*noise
        const float4* nr = (const float4*)(nz + (size_t)row * K_DIM);
        float4 n0 = nr[2 * tid], n1 = nr[2 * tid + 1];
        const float sc = __expf(0.5f * logvar[0]);
        float4 o0, o1;
        o0.x = fmaf(sc, n0.x, v0.x); o0.y = fmaf(sc, n0.y, v0.y);
        o0.z = fmaf(sc, n0.z, v0.z); o0.w = fmaf(sc, n0.w, v0.w);
        o1.x = fmaf(sc, n1.x, v1.x); o1.y = fmaf(sc, n1.y, v1.y);
        o1.z = fmaf(sc, n1.z, v1.z); o1.w = fmaf(sc, n1.w, v1.w);
        float4* tr = (float4*)(xt + (size_t)row * K_DIM);
        tr[2 * tid] = o0;
        tr[2 * tid + 1] = o1;
    }

    unsigned int* dst = xb + (size_t)row * ROW_U + tid * 2;
    dst[0] = pack4(v0.x, v0.y, v0.z, v0.w);
    dst[1] = pack4(v1.x, v1.y, v1.z, v1.w);

#pragma unroll
    for (int d = 32; d > 0; d >>= 1) s += __shfl_down(s, d);
    __shared__ float red[6];
    if ((tid & 63) == 0) red[tid >> 6] = s;
    __syncthreads();
    if (tid == 0) {
        float t = 0.f;
#pragma unroll
        for (int i = 0; i < 6; ++i) t += red[i];
        xn[row] = t;
        se[row] = 0.f;
    }
}

// ---------- kernel 2: 256x128 triangular i8 Gram, 3-buf counted-vmcnt, 2 blocks/CU ----------
__global__ __launch_bounds__(512, 4) void gram_lse_kernel(const unsigned int* __restrict__ xb,
                                                          const float* __restrict__ xn,
                                                          const float* __restrict__ logvar,
                                                          float* __restrict__ se)
{
    // per buffer: A 256x64B (16 KB) at [0], B 128x64B (8 KB) at [16384]  => 72 KiB total
    __shared__ __align__(1024) unsigned char lds[3][24576];

    // decode linear block id -> (a, v): a in [0,32), v in [2a, 64)
    int rem = blockIdx.x;
    int a = 0;
    while (rem >= NTB - 2 * a) { rem -= NTB - 2 * a; ++a; }
    const int v = 2 * a + rem;

    const int tid  = threadIdx.x;           // 512
    const int lane = tid & 63;
    const int wave = tid >> 6;              // 8 waves: 4(M) x 2(N)
    const int wr = wave >> 1, wc = wave & 1;
    const int fc = lane >> 4;               // 16B chunk group 0..3

    const size_t rowA0 = (size_t)a * BMA;
    const size_t rowB0 = (size_t)v * BNB;
    const unsigned char* xb8 = (const unsigned char*)xb;

    // staging: 3 slots/thread/K-tile (2 A + 1 B), 16 B each.
    // slot element e -> row r=e>>2, chunk c=e&3; source chunk PRE-SWIZZLED
    // (c ^ (r>>1)&3); LDS dest linear (rule #21).
    unsigned int srcOff[3];
    int dstOff[3];
#pragma unroll
    for (int l = 0; l < 3; ++l) {
        const int e = (l < 2) ? (l * 512 + tid) : tid;
        const int r = e >> 2, c = e & 3;
        const int csw = c ^ ((r >> 1) & 3);
        const size_t rb = ((l < 2) ? rowA0 : rowB0) + (size_t)r;
        srcOff[l] = (unsigned int)(rb * ROW_B + (size_t)csw * 16);
        dstOff[l] = ((l < 2) ? 0 : 16384) + e * 16;
    }

    i32x4 acc[4][4];
#pragma unroll
    for (int i = 0; i < 4; ++i)
#pragma unroll
        for (int j = 0; j < 4; ++j) acc[i][j] = (i32x4){0, 0, 0, 0};

    // prologue: stage K-tiles 0 and 1 into buffers 0 and 1
#pragma unroll
    for (int l = 0; l < 3; ++l)
        __builtin_amdgcn_global_load_lds(
            (const __attribute__((address_space(1))) void*)(xb8 + srcOff[l]),
            (__attribute__((address_space(3))) void*)(&lds[0][0] + dstOff[l]), 16, 0, 0);
#pragma unroll
    for (int l = 0; l < 3; ++l)
        __builtin_amdgcn_global_load_lds(
            (const __attribute__((address_space(1))) void*)(xb8 + srcOff[l] + 64u),
            (__attribute__((address_space(3))) void*)(&lds[1][0] + dstOff[l]), 16, 0, 0);
    asm volatile("s_waitcnt vmcnt(3)" ::: "memory");   // tile 0 landed; tile 1 in flight
    asm volatile("s_barrier" ::: "memory");

    for (int t = 0; t < NKT; ++t) {
        const unsigned char* cur = &lds[t % 3][0];

        // prefetch tile t+2 into buf (t+2)%3 (its last readers finished at
        // the end of iter t-1, strictly before this point)
        if (t + 2 < NKT) {
            unsigned char* nxt = &lds[(t + 2) % 3][0];
            const unsigned int kg = (unsigned int)(t + 2) * 64u;
#pragma unroll
            for (int l = 0; l < 3; ++l)
                __builtin_amdgcn_global_load_lds(
                    (const __attribute__((address_space(1))) void*)(xb8 + srcOff[l] + kg),
                    (__attribute__((address_space(3))) void*)(nxt + dstOff[l]), 16, 0, 0);
        }

        // fragment reads (swizzled, conflict-free): one b128 = one K=64 i8 fragment
        i32x4 aF[4], bF[4];
#pragma unroll
        for (int mi = 0; mi < 4; ++mi) {
            const int r = wr * 64 + mi * 16 + (lane & 15);
            const int phys = fc ^ ((r >> 1) & 3);
            aF[mi] = *(const i32x4*)(cur + r * 64 + phys * 16);
        }
#pragma unroll
        for (int ni = 0; ni < 4; ++ni) {
            const int r = wc * 64 + ni * 16 + (lane & 15);
            const int phys = fc ^ ((r >> 1) & 3);
            bF[ni] = *(const i32x4*)(cur + 16384 + r * 64 + phys * 16);
        }

        __builtin_amdgcn_s_setprio(1);
#pragma unroll
        for (int mi = 0; mi < 4; ++mi)
#pragma unroll
            for (int ni = 0; ni < 4; ++ni)
                acc[mi][ni] = __builtin_amdgcn_mfma_i32_16x16x64_i8(
                    aF[mi], bF[ni], acc[mi][ni], 0, 0, 0);
        __builtin_amdgcn_s_setprio(0);

        // counted fence: t+1's 3 loads (older) must land; t+2's 3 may stay in flight
        if (t + 2 < NKT)
            asm volatile("s_waitcnt vmcnt(3)" ::: "memory");
        else
            asm volatile("s_waitcnt vmcnt(0)" ::: "memory");
        asm volatile("s_barrier" ::: "memory");
    }

    // ---- fused epilogue: exp terms + row/col partial sums ----
    const float lv  = logvar[0];
    const float var = __expf(lv) + 1e-10f;
    const float cc  = 0.5f / var;

    const int u = 2 * a + (wr >> 1);        // this wave's 128-row cell index
    if (u > v) return;                      // below-diagonal half of a v==2a tile

    const int colBase = (int)rowB0 + wc * 64 + (lane & 15);
    const int rowBase = (int)rowA0 + wr * 64 + (lane >> 4) * 4;

    // row sums -> se[i]  (i==j override handles diagonal cells exactly)
#pragma unroll
    for (int mi = 0; mi < 4; ++mi) {
#pragma unroll
        for (int rg = 0; rg < 4; ++rg) {
            const int i = rowBase + mi * 16 + rg;
            const float xni = xn[i];
            float rs = 0.f;
#pragma unroll
            for (int ni = 0; ni < 4; ++ni) {
                const int j = colBase + ni * 16;
                const float g = (float)acc[mi][ni][rg] * INV_S2;
                const float dist = xni + xn[j] - 2.f * g;
                rs += (i == j) ? 1.0f : __expf(-cc * fmaxf(dist, 0.f));
            }
#pragma unroll
            for (int d = 1; d < 16; d <<= 1) rs += __shfl_xor(rs, d);
            if ((lane & 15) == 0) atomicAdd(&se[i], rs);
        }
    }

    // col-mirror sums -> se[j], strictly-off-diagonal cells only (i < j always)
    if (u < v) {
#pragma unroll
        for (int ni = 0; ni < 4; ++ni) {
            const int j = colBase + ni * 16;
            const float xnj = xn[j];
            float cs = 0.f;
#pragma unroll
            for (int mi = 0; mi < 4; ++mi)
#pragma unroll
                for (int rg = 0; rg < 4; ++rg) {
                    const int i = rowBase + mi * 16 + rg;
                    const float g = (float)acc[mi][ni][rg] * INV_S2;
                    cs += __expf(-cc * fmaxf(xn[i] + xnj - 2.f * g, 0.f));
                }
#pragma unroll
            for (int d = 16; d < 64; d <<= 1) cs += __shfl_xor(cs, d);
            if ((lane >> 4) == 0) atomicAdd(&se[j], cs);
        }
    }
}

// ---------- kernel 3: KL scalar ----------
__global__ __launch_bounds__(256) void kl_kernel(const float* __restrict__ se,
                                                 float* __restrict__ out)
{
    const int tid = threadIdx.x;
    float s = 0.f;
    for (int i = tid; i < B_DIM; i += 256) s += logf(se[i]);
#pragma unroll
    for (int d = 32; d > 0; d >>= 1) s += __shfl_down(s, d);
    __shared__ float red[4];
    if ((tid & 63) == 0) red[tid >> 6] = s;
    __syncthreads();
    if (tid == 0) {
        const float dc = -(red[0] + red[1] + red[2] + red[3]) / (float)B_DIM;
        out[0] = (logf((float)B_DIM) + dc) / logf(2.f);
    }
}

// ---------- kernel 4 (fallback path only): x_t elementwise ----------
__global__ __launch_bounds__(256) void xt_kernel(const float4* __restrict__ x,
                                                 const float4* __restrict__ nz,
                                                 const float* __restrict__ logvar,
                                                 float4* __restrict__ out, int n4)
{
    const float sc = expf(0.5f * logvar[0]);
    for (int i = blockIdx.x * blockDim.x + threadIdx.x; i < n4;
         i += gridDim.x * blockDim.x) {
        float4 va = x[i], vb = nz[i];
        float4 o;
        o.x = fmaf(sc, vb.x, va.x);
        o.y = fmaf(sc, vb.y, va.y);
        o.z = fmaf(sc, vb.z, va.z);
        o.w = fmaf(sc, vb.w, va.w);
        out[i] = o;
    }
}

extern "C" void kernel_launch(void* const* d_in, const int* in_sizes, int n_in,
                              void* d_out, int out_size, void* d_ws, size_t ws_size,
                              hipStream_t stream)
{
    const float* x      = (const float*)d_in[0];
    const float* noise  = (const float*)d_in[1];
    const float* logvar = (const float*)d_in[2];
    float* out = (float*)d_out;

    const size_t NEL      = (size_t)B_DIM * K_DIM;      // 25165824
    const size_t XB_BYTES = (size_t)B_DIM * ROW_B;      // 25165824 B
    const size_t NTILES   = 1056;                       // sum_{a<32} (64-2a)

    const bool use_ws = ws_size >= XB_BYTES + 2 * (size_t)B_DIM * sizeof(float) + 256;

    if (use_ws) {
        // xb/xn/se live in d_ws; x_t written directly by fused prep
        unsigned int* xb = (unsigned int*)d_ws;
        float* xn = (float*)((char*)d_ws + XB_BYTES);
        float* se = xn + B_DIM;

        prep_kernel<<<B_DIM, 384, 0, stream>>>(x, noise, logvar, out, xb, xn, se);
        gram_lse_kernel<<<(int)NTILES, 512, 0, stream>>>(xb, xn, logvar, se);
        kl_kernel<<<1, 256, 0, stream>>>(se, out + NEL);
    } else {
        // fallback: scratch carved from d_out, x_t written last
        unsigned int* xb = (unsigned int*)d_out;
        float* xn = (float*)((char*)d_out + (32u << 20));
        float* se = xn + B_DIM;

        prep_kernel<<<B_DIM, 384, 0, stream>>>(x, noise, logvar, nullptr, xb, xn, se);
        gram_lse_kernel<<<(int)NTILES, 512, 0, stream>>>(xb, xn, logvar, se);
        kl_kernel<<<1, 256, 0, stream>>>(se, out + NEL);
        xt_kernel<<<2048, 256, 0, stream>>>((const float4*)x, (const float4*)noise,
                                            logvar, (float4*)out, (int)(NEL / 4));
    }
}

// Round 12
// 210.549 us; speedup vs baseline: 1.1610x; 1.0007x over previous
//
#include <hip/hip_runtime.h>
#include <cstdint>

#define K_DIM 3072
#define B_DIM 8192
#define ROW_B 3072    /* bytes per i8 row */
#define ROW_U 768     /* u32 per i8 row */
#define BMA   256     /* A-rows per tile */
#define BNB   128     /* B-cols per tile */
#define NTB   64      /* 8192/128 col tiles */
#define NKT   48      /* K_DIM/64 K-tiles */
#define NTILES 1056   /* sum_{a<32} (64-2a) */
#define N4     6291456 /* B_DIM*K_DIM/4 float4s */

typedef __attribute__((ext_vector_type(4))) float        f32x4;
typedef __attribute__((ext_vector_type(4))) int          i32x4;

#define QS     16.0f          /* quant scale: q = rn(x*16), exact mul */
#define INV_S2 0.00390625f    /* 1/256 */

__device__ __forceinline__ int q8(float f) {
    int q = __float2int_rn(f * QS);
    return max(-127, min(127, q));
}
__device__ __forceinline__ unsigned pack4(float a, float b, float c, float d) {
    return (unsigned)(q8(a) & 0xFF)
         | ((unsigned)(q8(b) & 0xFF) << 8)
         | ((unsigned)(q8(c) & 0xFF) << 16)
         | ((unsigned)(q8(d) & 0xFF) << 24);
}

// ---------- kernel 1: i8 quantize (row-major) + row |x|^2 + zero se ----------
__global__ __launch_bounds__(384) void prep_kernel(const float* __restrict__ x,
                                                   unsigned int* __restrict__ xb,
                                                   float* __restrict__ xn,
                                                   float* __restrict__ se)
{
    const int row = blockIdx.x;
    const int tid = threadIdx.x;            // 384 threads: 8 consecutive floats each
    const float4* xr = (const float4*)(x + (size_t)row * K_DIM);
    float4 v0 = xr[2 * tid];
    float4 v1 = xr[2 * tid + 1];
    float s = v0.x * v0.x + v0.y * v0.y + v0.z * v0.z + v0.w * v0.w
            + v1.x * v1.x + v1.y * v1.y + v1.z * v1.z + v1.w * v1.w;

    unsigned int* dst = xb + (size_t)row * ROW_U + tid * 2;
    dst[0] = pack4(v0.x, v0.y, v0.z, v0.w);
    dst[1] = pack4(v1.x, v1.y, v1.z, v1.w);

#pragma unroll
    for (int d = 32; d > 0; d >>= 1) s += __shfl_down(s, d);
    __shared__ float red[6];
    if ((tid & 63) == 0) red[tid >> 6] = s;
    __syncthreads();
    if (tid == 0) {
        float t = 0.f;
#pragma unroll
        for (int i = 0; i < 6; ++i) t += red[i];
        xn[row] = t;
        se[row] = 0.f;
    }
}

// ---------- kernel 2: 256x128 triangular i8 Gram, 3-buf counted-vmcnt, 2 blocks/CU,
//            + fused x_t stream in the epilogue (overlaps gram's idle HBM) ----------
__global__ __launch_bounds__(512, 4) void gram_lse_kernel(const unsigned int* __restrict__ xb,
                                                          const float* __restrict__ xn,
                                                          const float* __restrict__ logvar,
                                                          float* __restrict__ se,
                                                          const float4* __restrict__ x4,
                                                          const float4* __restrict__ nz4,
                                                          float4* __restrict__ xt4)  // may be null
{
    // per buffer: A 256x64B (16 KB) at [0], B 128x64B (8 KB) at [16384]  => 72 KiB total
    __shared__ __align__(1024) unsigned char lds[3][24576];

    // decode linear block id -> (a, v): a in [0,32), v in [2a, 64)
    int rem = blockIdx.x;
    int a = 0;
    while (rem >= NTB - 2 * a) { rem -= NTB - 2 * a; ++a; }
    const int v = 2 * a + rem;

    const int tid  = threadIdx.x;           // 512
    const int lane = tid & 63;
    const int wave = tid >> 6;              // 8 waves: 4(M) x 2(N)
    const int wr = wave >> 1, wc = wave & 1;
    const int fc = lane >> 4;               // 16B chunk group 0..3

    const size_t rowA0 = (size_t)a * BMA;
    const size_t rowB0 = (size_t)v * BNB;
    const unsigned char* xb8 = (const unsigned char*)xb;

    // staging: 3 slots/thread/K-tile (2 A + 1 B), 16 B each.
    // slot element e -> row r=e>>2, chunk c=e&3; source chunk PRE-SWIZZLED
    // (c ^ (r>>1)&3); LDS dest linear (rule #21).
    unsigned int srcOff[3];
    int dstOff[3];
#pragma unroll
    for (int l = 0; l < 3; ++l) {
        const int e = (l < 2) ? (l * 512 + tid) : tid;
        const int r = e >> 2, c = e & 3;
        const int csw = c ^ ((r >> 1) & 3);
        const size_t rb = ((l < 2) ? rowA0 : rowB0) + (size_t)r;
        srcOff[l] = (unsigned int)(rb * ROW_B + (size_t)csw * 16);
        dstOff[l] = ((l < 2) ? 0 : 16384) + e * 16;
    }

    i32x4 acc[4][4];
#pragma unroll
    for (int i = 0; i < 4; ++i)
#pragma unroll
        for (int j = 0; j < 4; ++j) acc[i][j] = (i32x4){0, 0, 0, 0};

    // prologue: stage K-tiles 0 and 1 into buffers 0 and 1
#pragma unroll
    for (int l = 0; l < 3; ++l)
        __builtin_amdgcn_global_load_lds(
            (const __attribute__((address_space(1))) void*)(xb8 + srcOff[l]),
            (__attribute__((address_space(3))) void*)(&lds[0][0] + dstOff[l]), 16, 0, 0);
#pragma unroll
    for (int l = 0; l < 3; ++l)
        __builtin_amdgcn_global_load_lds(
            (const __attribute__((address_space(1))) void*)(xb8 + srcOff[l] + 64u),
            (__attribute__((address_space(3))) void*)(&lds[1][0] + dstOff[l]), 16, 0, 0);
    asm volatile("s_waitcnt vmcnt(3)" ::: "memory");   // tile 0 landed; tile 1 in flight
    asm volatile("s_barrier" ::: "memory");

    for (int t = 0; t < NKT; ++t) {
        const unsigned char* cur = &lds[t % 3][0];

        // prefetch tile t+2 into buf (t+2)%3 (its last readers finished at
        // the end of iter t-1, strictly before this point)
        if (t + 2 < NKT) {
            unsigned char* nxt = &lds[(t + 2) % 3][0];
            const unsigned int kg = (unsigned int)(t + 2) * 64u;
#pragma unroll
            for (int l = 0; l < 3; ++l)
                __builtin_amdgcn_global_load_lds(
                    (const __attribute__((address_space(1))) void*)(xb8 + srcOff[l] + kg),
                    (__attribute__((address_space(3))) void*)(nxt + dstOff[l]), 16, 0, 0);
        }

        // fragment reads (swizzled, conflict-free): one b128 = one K=64 i8 fragment
        i32x4 aF[4], bF[4];
#pragma unroll
        for (int mi = 0; mi < 4; ++mi) {
            const int r = wr * 64 + mi * 16 + (lane & 15);
            const int phys = fc ^ ((r >> 1) & 3);
            aF[mi] = *(const i32x4*)(cur + r * 64 + phys * 16);
        }
#pragma unroll
        for (int ni = 0; ni < 4; ++ni) {
            const int r = wc * 64 + ni * 16 + (lane & 15);
            const int phys = fc ^ ((r >> 1) & 3);
            bF[ni] = *(const i32x4*)(cur + 16384 + r * 64 + phys * 16);
        }

        __builtin_amdgcn_s_setprio(1);
#pragma unroll
        for (int mi = 0; mi < 4; ++mi)
#pragma unroll
            for (int ni = 0; ni < 4; ++ni)
                acc[mi][ni] = __builtin_amdgcn_mfma_i32_16x16x64_i8(
                    aF[mi], bF[ni], acc[mi][ni], 0, 0, 0);
        __builtin_amdgcn_s_setprio(0);

        // counted fence: t+1's 3 loads (older) must land; t+2's 3 may stay in flight
        if (t + 2 < NKT)
            asm volatile("s_waitcnt vmcnt(3)" ::: "memory");
        else
            asm volatile("s_waitcnt vmcnt(0)" ::: "memory");
        asm volatile("s_barrier" ::: "memory");
    }

    const float lv  = logvar[0];

    // ---- fused x_t stream: this block's slice of x_t = x + exp(0.5*lv)*noise.
    // Placed BEFORE the per-wave early-return so all 512 threads participate.
    // ~300 MB across 1056 blocks, overlapping gram rounds still in flight.
    if (xt4) {
        const float sc = __expf(0.5f * lv);
        for (int i = blockIdx.x * 512 + tid; i < N4; i += NTILES * 512) {
            float4 va = x4[i], vb = nz4[i];
            float4 o;
            o.x = fmaf(sc, vb.x, va.x);
            o.y = fmaf(sc, vb.y, va.y);
            o.z = fmaf(sc, vb.z, va.z);
            o.w = fmaf(sc, vb.w, va.w);
            xt4[i] = o;
        }
    }

    // ---- fused epilogue: exp terms + row/col partial sums ----
    const float var = __expf(lv) + 1e-10f;
    const float cc  = 0.5f / var;

    const int u = 2 * a + (wr >> 1);        // this wave's 128-row cell index
    if (u > v) return;                      // below-diagonal half of a v==2a tile

    const int colBase = (int)rowB0 + wc * 64 + (lane & 15);
    const int rowBase = (int)rowA0 + wr * 64 + (lane >> 4) * 4;

    // row sums -> se[i]  (i==j override handles diagonal cells exactly)
#pragma unroll
    for (int mi = 0; mi < 4; ++mi) {
#pragma unroll
        for (int rg = 0; rg < 4; ++rg) {
            const int i = rowBase + mi * 16 + rg;
            const float xni = xn[i];
            float rs = 0.f;
#pragma unroll
            for (int ni = 0; ni < 4; ++ni) {
                const int j = colBase + ni * 16;
                const float g = (float)acc[mi][ni][rg] * INV_S2;
                const float dist = xni + xn[j] - 2.f * g;
                rs += (i == j) ? 1.0f : __expf(-cc * fmaxf(dist, 0.f));
            }
#pragma unroll
            for (int d = 1; d < 16; d <<= 1) rs += __shfl_xor(rs, d);
            if ((lane & 15) == 0) atomicAdd(&se[i], rs);
        }
    }

    // col-mirror sums -> se[j], strictly-off-diagonal cells only (i < j always)
    if (u < v) {
#pragma unroll
        for (int ni = 0; ni < 4; ++ni) {
            const int j = colBase + ni * 16;
            const float xnj = xn[j];
            float cs = 0.f;
#pragma unroll
            for (int mi = 0; mi < 4; ++mi)
#pragma unroll
                for (int rg = 0; rg < 4; ++rg) {
                    const int i = rowBase + mi * 16 + rg;
                    const float g = (float)acc[mi][ni][rg] * INV_S2;
                    cs += __expf(-cc * fmaxf(xn[i] + xnj - 2.f * g, 0.f));
                }
#pragma unroll
            for (int d = 16; d < 64; d <<= 1) cs += __shfl_xor(cs, d);
            if ((lane >> 4) == 0) atomicAdd(&se[j], cs);
        }
    }
}

// ---------- kernel 3: KL scalar ----------
__global__ __launch_bounds__(256) void kl_kernel(const float* __restrict__ se,
                                                 float* __restrict__ out)
{
    const int tid = threadIdx.x;
    float s = 0.f;
    for (int i = tid; i < B_DIM; i += 256) s += logf(se[i]);
#pragma unroll
    for (int d = 32; d > 0; d >>= 1) s += __shfl_down(s, d);
    __shared__ float red[4];
    if ((tid & 63) == 0) red[tid >> 6] = s;
    __syncthreads();
    if (tid == 0) {
        const float dc = -(red[0] + red[1] + red[2] + red[3]) / (float)B_DIM;
        out[0] = (logf((float)B_DIM) + dc) / logf(2.f);
    }
}

// ---------- kernel 4 (fallback path only): x_t elementwise ----------
__global__ __launch_bounds__(256) void xt_kernel(const float4* __restrict__ x,
                                                 const float4* __restrict__ nz,
                                                 const float* __restrict__ logvar,
                                                 float4* __restrict__ out, int n4)
{
    const float sc = expf(0.5f * logvar[0]);
    for (int i = blockIdx.x * blockDim.x + threadIdx.x; i < n4;
         i += gridDim.x * blockDim.x) {
        float4 va = x[i], vb = nz[i];
        float4 o;
        o.x = fmaf(sc, vb.x, va.x);
        o.y = fmaf(sc, vb.y, va.y);
        o.z = fmaf(sc, vb.z, va.z);
        o.w = fmaf(sc, vb.w, va.w);
        out[i] = o;
    }
}

extern "C" void kernel_launch(void* const* d_in, const int* in_sizes, int n_in,
                              void* d_out, int out_size, void* d_ws, size_t ws_size,
                              hipStream_t stream)
{
    const float* x      = (const float*)d_in[0];
    const float* noise  = (const float*)d_in[1];
    const float* logvar = (const float*)d_in[2];
    float* out = (float*)d_out;

    const size_t NEL      = (size_t)B_DIM * K_DIM;      // 25165824
    const size_t XB_BYTES = (size_t)B_DIM * ROW_B;      // 25165824 B

    const bool use_ws = ws_size >= XB_BYTES + 2 * (size_t)B_DIM * sizeof(float) + 256;

    if (use_ws) {
        // xb/xn/se live in d_ws; x_t streamed from gram's epilogue
        unsigned int* xb = (unsigned int*)d_ws;
        float* xn = (float*)((char*)d_ws + XB_BYTES);
        float* se = xn + B_DIM;

        prep_kernel<<<B_DIM, 384, 0, stream>>>(x, xb, xn, se);
        gram_lse_kernel<<<NTILES, 512, 0, stream>>>(xb, xn, logvar, se,
                                                    (const float4*)x,
                                                    (const float4*)noise,
                                                    (float4*)out);
        kl_kernel<<<1, 256, 0, stream>>>(se, out + NEL);
    } else {
        // fallback: scratch carved from d_out; x_t must wait until gram is done
        unsigned int* xb = (unsigned int*)d_out;
        float* xn = (float*)((char*)d_out + (32u << 20));
        float* se = xn + B_DIM;

        prep_kernel<<<B_DIM, 384, 0, stream>>>(x, xb, xn, se);
        gram_lse_kernel<<<NTILES, 512, 0, stream>>>(xb, xn, logvar, se,
                                                    (const float4*)x,
                                                    (const float4*)noise,
                                                    nullptr);
        kl_kernel<<<1, 256, 0, stream>>>(se, out + NEL);
        xt_kernel<<<2048, 256, 0, stream>>>((const float4*)x, (const float4*)noise,
                                            logvar, (float4*)out, (int)(NEL / 4));
    }
}

// Round 13
// 207.957 us; speedup vs baseline: 1.1754x; 1.0125x over previous
//
#include <hip/hip_runtime.h>
#include <cstdint>

#define K_DIM 3072
#define B_DIM 8192
#define ROW_B 3072    /* bytes per i8 row */
#define ROW_U 768     /* u32 per i8 row */
#define BMA   256     /* A-rows per tile */
#define BNB   128     /* B-cols per tile */
#define NTB   64      /* 8192/128 col tiles */
#define NKT   48      /* K_DIM/64 K-tiles */
#define NTILES 1056   /* sum_{a<32} (64-2a) */
#define N4     6291456 /* B_DIM*K_DIM/4 float4s */

typedef __attribute__((ext_vector_type(4))) float        f32x4;
typedef __attribute__((ext_vector_type(4))) int          i32x4;

#define QS     16.0f          /* quant scale: q = rn(x*16), exact mul */
#define INV_S2 0.00390625f    /* 1/256 */

__device__ __forceinline__ int q8(float f) {
    int q = __float2int_rn(f * QS);
    return max(-127, min(127, q));
}
__device__ __forceinline__ unsigned pack4(float a, float b, float c, float d) {
    return (unsigned)(q8(a) & 0xFF)
         | ((unsigned)(q8(b) & 0xFF) << 8)
         | ((unsigned)(q8(c) & 0xFF) << 16)
         | ((unsigned)(q8(d) & 0xFF) << 24);
}

// ---------- kernel 1: i8 quantize (row-major) + row |x|^2 + zero se ----------
__global__ __launch_bounds__(384) void prep_kernel(const float* __restrict__ x,
                                                   unsigned int* __restrict__ xb,
                                                   float* __restrict__ xn,
                                                   float* __restrict__ se)
{
    const int row = blockIdx.x;
    const int tid = threadIdx.x;            // 384 threads: 8 consecutive floats each
    const float4* xr = (const float4*)(x + (size_t)row * K_DIM);
    float4 v0 = xr[2 * tid];
    float4 v1 = xr[2 * tid + 1];
    float s = v0.x * v0.x + v0.y * v0.y + v0.z * v0.z + v0.w * v0.w
            + v1.x * v1.x + v1.y * v1.y + v1.z * v1.z + v1.w * v1.w;

    unsigned int* dst = xb + (size_t)row * ROW_U + tid * 2;
    dst[0] = pack4(v0.x, v0.y, v0.z, v0.w);
    dst[1] = pack4(v1.x, v1.y, v1.z, v1.w);

#pragma unroll
    for (int d = 32; d > 0; d >>= 1) s += __shfl_down(s, d);
    __shared__ float red[6];
    if ((tid & 63) == 0) red[tid >> 6] = s;
    __syncthreads();
    if (tid == 0) {
        float t = 0.f;
#pragma unroll
        for (int i = 0; i < 6; ++i) t += red[i];
        xn[row] = t;
        se[row] = 0.f;
    }
}

// ---------- kernel 2: 256x128 triangular i8 Gram, 3-buf counted-vmcnt, 2 blocks/CU,
//            + x_t stream interleaved INTO the K-loop (idle-HBM overlap) ----------
__global__ __launch_bounds__(512, 4) void gram_lse_kernel(const unsigned int* __restrict__ xb,
                                                          const float* __restrict__ xn,
                                                          const float* __restrict__ logvar,
                                                          float* __restrict__ se,
                                                          const float4* __restrict__ x4,
                                                          const float4* __restrict__ nz4,
                                                          float4* __restrict__ xt4)  // may be null
{
    // per buffer: A 256x64B (16 KB) at [0], B 128x64B (8 KB) at [16384]  => 72 KiB total
    __shared__ __align__(1024) unsigned char lds[3][24576];

    // decode linear block id -> (a, v): a in [0,32), v in [2a, 64)
    int rem = blockIdx.x;
    int a = 0;
    while (rem >= NTB - 2 * a) { rem -= NTB - 2 * a; ++a; }
    const int v = 2 * a + rem;

    const int tid  = threadIdx.x;           // 512
    const int lane = tid & 63;
    const int wave = tid >> 6;              // 8 waves: 4(M) x 2(N)
    const int wr = wave >> 1, wc = wave & 1;
    const int fc = lane >> 4;               // 16B chunk group 0..3

    const size_t rowA0 = (size_t)a * BMA;
    const size_t rowB0 = (size_t)v * BNB;
    const unsigned char* xb8 = (const unsigned char*)xb;

    const float lv = logvar[0];
    const float sc = __expf(0.5f * lv);
    const int xtBase = blockIdx.x * 512 + tid;   // this thread's x_t slice base

    // staging: 3 slots/thread/K-tile (2 A + 1 B), 16 B each.
    // slot element e -> row r=e>>2, chunk c=e&3; source chunk PRE-SWIZZLED
    // (c ^ (r>>1)&3); LDS dest linear (rule #21).
    unsigned int srcOff[3];
    int dstOff[3];
#pragma unroll
    for (int l = 0; l < 3; ++l) {
        const int e = (l < 2) ? (l * 512 + tid) : tid;
        const int r = e >> 2, c = e & 3;
        const int csw = c ^ ((r >> 1) & 3);
        const size_t rb = ((l < 2) ? rowA0 : rowB0) + (size_t)r;
        srcOff[l] = (unsigned int)(rb * ROW_B + (size_t)csw * 16);
        dstOff[l] = ((l < 2) ? 0 : 16384) + e * 16;
    }

    i32x4 acc[4][4];
#pragma unroll
    for (int i = 0; i < 4; ++i)
#pragma unroll
        for (int j = 0; j < 4; ++j) acc[i][j] = (i32x4){0, 0, 0, 0};

    // prologue: stage K-tiles 0 and 1 into buffers 0 and 1
#pragma unroll
    for (int l = 0; l < 3; ++l)
        __builtin_amdgcn_global_load_lds(
            (const __attribute__((address_space(1))) void*)(xb8 + srcOff[l]),
            (__attribute__((address_space(3))) void*)(&lds[0][0] + dstOff[l]), 16, 0, 0);
#pragma unroll
    for (int l = 0; l < 3; ++l)
        __builtin_amdgcn_global_load_lds(
            (const __attribute__((address_space(1))) void*)(xb8 + srcOff[l] + 64u),
            (__attribute__((address_space(3))) void*)(&lds[1][0] + dstOff[l]), 16, 0, 0);
    asm volatile("s_waitcnt vmcnt(3)" ::: "memory");   // tile 0 landed; tile 1 in flight
    asm volatile("s_barrier" ::: "memory");

    for (int t = 0; t < NKT; ++t) {
        const unsigned char* cur = &lds[t % 3][0];

        // interleaved x_t slice: one float4 per thread every 4th iter (12 slices).
        // Issued BEFORE this iter's prefetch => at the end-of-iter vmcnt(3) fence
        // these are among the waited ops (full-iteration slack), and the fence's
        // "tile t+1 landed" guarantee is unchanged (it waits all but the 3 newest).
        if (xt4 && (t & 3) == 0) {
            const int i = xtBase + (t >> 2) * (NTILES * 512);
            if (i < N4) {
                float4 va = x4[i], vb = nz4[i];
                float4 o;
                o.x = fmaf(sc, vb.x, va.x);
                o.y = fmaf(sc, vb.y, va.y);
                o.z = fmaf(sc, vb.z, va.z);
                o.w = fmaf(sc, vb.w, va.w);
                xt4[i] = o;
            }
        }

        // prefetch tile t+2 into buf (t+2)%3 (its last readers finished at
        // the end of iter t-1, strictly before this point)
        if (t + 2 < NKT) {
            unsigned char* nxt = &lds[(t + 2) % 3][0];
            const unsigned int kg = (unsigned int)(t + 2) * 64u;
#pragma unroll
            for (int l = 0; l < 3; ++l)
                __builtin_amdgcn_global_load_lds(
                    (const __attribute__((address_space(1))) void*)(xb8 + srcOff[l] + kg),
                    (__attribute__((address_space(3))) void*)(nxt + dstOff[l]), 16, 0, 0);
        }

        // fragment reads (swizzled, conflict-free): one b128 = one K=64 i8 fragment
        i32x4 aF[4], bF[4];
#pragma unroll
        for (int mi = 0; mi < 4; ++mi) {
            const int r = wr * 64 + mi * 16 + (lane & 15);
            const int phys = fc ^ ((r >> 1) & 3);
            aF[mi] = *(const i32x4*)(cur + r * 64 + phys * 16);
        }
#pragma unroll
        for (int ni = 0; ni < 4; ++ni) {
            const int r = wc * 64 + ni * 16 + (lane & 15);
            const int phys = fc ^ ((r >> 1) & 3);
            bF[ni] = *(const i32x4*)(cur + 16384 + r * 64 + phys * 16);
        }

        __builtin_amdgcn_s_setprio(1);
#pragma unroll
        for (int mi = 0; mi < 4; ++mi)
#pragma unroll
            for (int ni = 0; ni < 4; ++ni)
                acc[mi][ni] = __builtin_amdgcn_mfma_i32_16x16x64_i8(
                    aF[mi], bF[ni], acc[mi][ni], 0, 0, 0);
        __builtin_amdgcn_s_setprio(0);

        // counted fence: all but the 3 newest (tile t+2's gloads) must land --
        // i.e. tile t+1 staged AND this iter's xt ops done; t+2 stays in flight
        if (t + 2 < NKT)
            asm volatile("s_waitcnt vmcnt(3)" ::: "memory");
        else
            asm volatile("s_waitcnt vmcnt(0)" ::: "memory");
        asm volatile("s_barrier" ::: "memory");
    }

    // ---- fused epilogue: exp terms + row/col partial sums ----
    const float var = __expf(lv) + 1e-10f;
    const float cc  = 0.5f / var;

    const int u = 2 * a + (wr >> 1);        // this wave's 128-row cell index
    if (u > v) return;                      // below-diagonal half of a v==2a tile

    const int colBase = (int)rowB0 + wc * 64 + (lane & 15);
    const int rowBase = (int)rowA0 + wr * 64 + (lane >> 4) * 4;

    // row sums -> se[i]  (i==j override handles diagonal cells exactly)
#pragma unroll
    for (int mi = 0; mi < 4; ++mi) {
#pragma unroll
        for (int rg = 0; rg < 4; ++rg) {
            const int i = rowBase + mi * 16 + rg;
            const float xni = xn[i];
            float rs = 0.f;
#pragma unroll
            for (int ni = 0; ni < 4; ++ni) {
                const int j = colBase + ni * 16;
                const float g = (float)acc[mi][ni][rg] * INV_S2;
                const float dist = xni + xn[j] - 2.f * g;
                rs += (i == j) ? 1.0f : __expf(-cc * fmaxf(dist, 0.f));
            }
#pragma unroll
            for (int d = 1; d < 16; d <<= 1) rs += __shfl_xor(rs, d);
            if ((lane & 15) == 0) atomicAdd(&se[i], rs);
        }
    }

    // col-mirror sums -> se[j], strictly-off-diagonal cells only (i < j always)
    if (u < v) {
#pragma unroll
        for (int ni = 0; ni < 4; ++ni) {
            const int j = colBase + ni * 16;
            const float xnj = xn[j];
            float cs = 0.f;
#pragma unroll
            for (int mi = 0; mi < 4; ++mi)
#pragma unroll
                for (int rg = 0; rg < 4; ++rg) {
                    const int i = rowBase + mi * 16 + rg;
                    const float g = (float)acc[mi][ni][rg] * INV_S2;
                    cs += __expf(-cc * fmaxf(xn[i] + xnj - 2.f * g, 0.f));
                }
#pragma unroll
            for (int d = 16; d < 64; d <<= 1) cs += __shfl_xor(cs, d);
            if ((lane >> 4) == 0) atomicAdd(&se[j], cs);
        }
    }
}

// ---------- kernel 3: KL scalar ----------
__global__ __launch_bounds__(256) void kl_kernel(const float* __restrict__ se,
                                                 float* __restrict__ out)
{
    const int tid = threadIdx.x;
    float s = 0.f;
    for (int i = tid; i < B_DIM; i += 256) s += logf(se[i]);
#pragma unroll
    for (int d = 32; d > 0; d >>= 1) s += __shfl_down(s, d);
    __shared__ float red[4];
    if ((tid & 63) == 0) red[tid >> 6] = s;
    __syncthreads();
    if (tid == 0) {
        const float dc = -(red[0] + red[1] + red[2] + red[3]) / (float)B_DIM;
        out[0] = (logf((float)B_DIM) + dc) / logf(2.f);
    }
}

// ---------- kernel 4 (fallback path only): x_t elementwise ----------
__global__ __launch_bounds__(256) void xt_kernel(const float4* __restrict__ x,
                                                 const float4* __restrict__ nz,
                                                 const float* __restrict__ logvar,
                                                 float4* __restrict__ out, int n4)
{
    const float sc = expf(0.5f * logvar[0]);
    for (int i = blockIdx.x * blockDim.x + threadIdx.x; i < n4;
         i += gridDim.x * blockDim.x) {
        float4 va = x[i], vb = nz[i];
        float4 o;
        o.x = fmaf(sc, vb.x, va.x);
        o.y = fmaf(sc, vb.y, va.y);
        o.z = fmaf(sc, vb.z, va.z);
        o.w = fmaf(sc, vb.w, va.w);
        out[i] = o;
    }
}

extern "C" void kernel_launch(void* const* d_in, const int* in_sizes, int n_in,
                              void* d_out, int out_size, void* d_ws, size_t ws_size,
                              hipStream_t stream)
{
    const float* x      = (const float*)d_in[0];
    const float* noise  = (const float*)d_in[1];
    const float* logvar = (const float*)d_in[2];
    float* out = (float*)d_out;

    const size_t NEL      = (size_t)B_DIM * K_DIM;      // 25165824
    const size_t XB_BYTES = (size_t)B_DIM * ROW_B;      // 25165824 B

    const bool use_ws = ws_size >= XB_BYTES + 2 * (size_t)B_DIM * sizeof(float) + 256;

    if (use_ws) {
        // xb/xn/se live in d_ws; x_t streamed from inside gram's K-loop
        unsigned int* xb = (unsigned int*)d_ws;
        float* xn = (float*)((char*)d_ws + XB_BYTES);
        float* se = xn + B_DIM;

        prep_kernel<<<B_DIM, 384, 0, stream>>>(x, xb, xn, se);
        gram_lse_kernel<<<NTILES, 512, 0, stream>>>(xb, xn, logvar, se,
                                                    (const float4*)x,
                                                    (const float4*)noise,
                                                    (float4*)out);
        kl_kernel<<<1, 256, 0, stream>>>(se, out + NEL);
    } else {
        // fallback: scratch carved from d_out; x_t must wait until gram is done
        unsigned int* xb = (unsigned int*)d_out;
        float* xn = (float*)((char*)d_out + (32u << 20));
        float* se = xn + B_DIM;

        prep_kernel<<<B_DIM, 384, 0, stream>>>(x, xb, xn, se);
        gram_lse_kernel<<<NTILES, 512, 0, stream>>>(xb, xn, logvar, se,
                                                    (const float4*)x,
                                                    (const float4*)noise,
                                                    nullptr);
        kl_kernel<<<1, 256, 0, stream>>>(se, out + NEL);
        xt_kernel<<<2048, 256, 0, stream>>>((const float4*)x, (const float4*)noise,
                                            logvar, (float4*)out, (int)(NEL / 4));
    }
}

// Round 14
// 205.556 us; speedup vs baseline: 1.1892x; 1.0117x over previous
//
#include <hip/hip_runtime.h>
#include <cstdint>

#define K_DIM 3072
#define B_DIM 8192
#define ROW_B 3072    /* bytes per i8 row */
#define ROW_U 768     /* u32 per i8 row */
#define BMA   256     /* A-rows per tile */
#define BNB   128     /* B-cols per tile */
#define NTB   64      /* 8192/128 col tiles */
#define NKT   48      /* K_DIM/64 K-tiles */
#define NTILES 1056   /* sum_{a<32} (64-2a) */
#define N4     6291456 /* B_DIM*K_DIM/4 float4s */

typedef __attribute__((ext_vector_type(4))) float        f32x4;
typedef __attribute__((ext_vector_type(4))) int          i32x4;

#define QS     16.0f          /* quant scale: q = rn(x*16), exact mul */
#define INV_S2 0.00390625f    /* 1/256 */

__device__ __forceinline__ int q8(float f) {
    int q = __float2int_rn(f * QS);
    return max(-127, min(127, q));
}
__device__ __forceinline__ unsigned pack4(float a, float b, float c, float d) {
    return (unsigned)(q8(a) & 0xFF)
         | ((unsigned)(q8(b) & 0xFF) << 8)
         | ((unsigned)(q8(c) & 0xFF) << 16)
         | ((unsigned)(q8(d) & 0xFF) << 24);
}

// ---------- kernel 1: i8 quantize (row-major) + row |x|^2 + zero se ----------
__global__ __launch_bounds__(384) void prep_kernel(const float* __restrict__ x,
                                                   unsigned int* __restrict__ xb,
                                                   float* __restrict__ xn,
                                                   float* __restrict__ se)
{
    const int row = blockIdx.x;
    const int tid = threadIdx.x;            // 384 threads: 8 consecutive floats each
    const float4* xr = (const float4*)(x + (size_t)row * K_DIM);
    float4 v0 = xr[2 * tid];
    float4 v1 = xr[2 * tid + 1];
    float s = v0.x * v0.x + v0.y * v0.y + v0.z * v0.z + v0.w * v0.w
            + v1.x * v1.x + v1.y * v1.y + v1.z * v1.z + v1.w * v1.w;

    unsigned int* dst = xb + (size_t)row * ROW_U + tid * 2;
    dst[0] = pack4(v0.x, v0.y, v0.z, v0.w);
    dst[1] = pack4(v1.x, v1.y, v1.z, v1.w);

#pragma unroll
    for (int d = 32; d > 0; d >>= 1) s += __shfl_down(s, d);
    __shared__ float red[6];
    if ((tid & 63) == 0) red[tid >> 6] = s;
    __syncthreads();
    if (tid == 0) {
        float t = 0.f;
#pragma unroll
        for (int i = 0; i < 6; ++i) t += red[i];
        xn[row] = t;
        se[row] = 0.f;
    }
}

// ---------- kernel 2: 256x128 triangular i8 Gram, 3-buf counted-vmcnt, 2 blocks/CU,
//            + x_t stream software-pipelined INTO the K-loop (4-iter load/use gap) ----------
__global__ __launch_bounds__(512, 4) void gram_lse_kernel(const unsigned int* __restrict__ xb,
                                                          const float* __restrict__ xn,
                                                          const float* __restrict__ logvar,
                                                          float* __restrict__ se,
                                                          const float4* __restrict__ x4,
                                                          const float4* __restrict__ nz4,
                                                          float4* __restrict__ xt4)  // may be null
{
    // per buffer: A 256x64B (16 KB) at [0], B 128x64B (8 KB) at [16384]  => 72 KiB total
    __shared__ __align__(1024) unsigned char lds[3][24576];

    // decode linear block id -> (a, v): a in [0,32), v in [2a, 64)
    int rem = blockIdx.x;
    int a = 0;
    while (rem >= NTB - 2 * a) { rem -= NTB - 2 * a; ++a; }
    const int v = 2 * a + rem;

    const int tid  = threadIdx.x;           // 512
    const int lane = tid & 63;
    const int wave = tid >> 6;              // 8 waves: 4(M) x 2(N)
    const int wr = wave >> 1, wc = wave & 1;
    const int fc = lane >> 4;               // 16B chunk group 0..3

    const size_t rowA0 = (size_t)a * BMA;
    const size_t rowB0 = (size_t)v * BNB;
    const unsigned char* xb8 = (const unsigned char*)xb;

    const float lv = logvar[0];
    const float sc = __expf(0.5f * lv);
    const int xtBase = blockIdx.x * 512 + tid;   // this thread's x_t slice base

    // staging: 3 slots/thread/K-tile (2 A + 1 B), 16 B each.
    // slot element e -> row r=e>>2, chunk c=e&3; source chunk PRE-SWIZZLED
    // (c ^ (r>>1)&3); LDS dest linear (rule #21).
    unsigned int srcOff[3];
    int dstOff[3];
#pragma unroll
    for (int l = 0; l < 3; ++l) {
        const int e = (l < 2) ? (l * 512 + tid) : tid;
        const int r = e >> 2, c = e & 3;
        const int csw = c ^ ((r >> 1) & 3);
        const size_t rb = ((l < 2) ? rowA0 : rowB0) + (size_t)r;
        srcOff[l] = (unsigned int)(rb * ROW_B + (size_t)csw * 16);
        dstOff[l] = ((l < 2) ? 0 : 16384) + e * 16;
    }

    i32x4 acc[4][4];
#pragma unroll
    for (int i = 0; i < 4; ++i)
#pragma unroll
        for (int j = 0; j < 4; ++j) acc[i][j] = (i32x4){0, 0, 0, 0};

    // prologue: stage K-tiles 0 and 1 into buffers 0 and 1
#pragma unroll
    for (int l = 0; l < 3; ++l)
        __builtin_amdgcn_global_load_lds(
            (const __attribute__((address_space(1))) void*)(xb8 + srcOff[l]),
            (__attribute__((address_space(3))) void*)(&lds[0][0] + dstOff[l]), 16, 0, 0);
#pragma unroll
    for (int l = 0; l < 3; ++l)
        __builtin_amdgcn_global_load_lds(
            (const __attribute__((address_space(1))) void*)(xb8 + srcOff[l] + 64u),
            (__attribute__((address_space(3))) void*)(&lds[1][0] + dstOff[l]), 16, 0, 0);
    asm volatile("s_waitcnt vmcnt(3)" ::: "memory");   // tile 0 landed; tile 1 in flight
    asm volatile("s_barrier" ::: "memory");

    // x_t pipeline state: loads issued at xt-iter s are consumed at xt-iter s+1
    // (4 K-iterations later, ~2600 cyc slack >> HBM latency -> no dependent stall)
    float4 vaP, vbP;
    int iP = -1;

    for (int t = 0; t < NKT; ++t) {
        const unsigned char* cur = &lds[t % 3][0];
        const bool xt_iter = (xt4 != nullptr) && ((t & 3) == 0);

        if (xt_iter) {
            // 1a. store slice s-1 (registers loaded 4 iters ago; wait already satisfied)
            if (iP >= 0) {
                float4 o;
                o.x = fmaf(sc, vbP.x, vaP.x);
                o.y = fmaf(sc, vbP.y, vaP.y);
                o.z = fmaf(sc, vbP.z, vaP.z);
                o.w = fmaf(sc, vbP.w, vaP.w);
                xt4[iP] = o;
            }
            // 1b. issue loads for slice s = t>>2
            const int i = xtBase + (t >> 2) * (NTILES * 512);
            if (i < N4) {
                vaP = x4[i];
                vbP = nz4[i];
                iP = i;
            } else {
                iP = -1;
            }
        }

        // 2. prefetch tile t+2 into buf (t+2)%3 (its last readers finished at
        // the end of iter t-1, strictly before this point)
        if (t + 2 < NKT) {
            unsigned char* nxt = &lds[(t + 2) % 3][0];
            const unsigned int kg = (unsigned int)(t + 2) * 64u;
#pragma unroll
            for (int l = 0; l < 3; ++l)
                __builtin_amdgcn_global_load_lds(
                    (const __attribute__((address_space(1))) void*)(xb8 + srcOff[l] + kg),
                    (__attribute__((address_space(3))) void*)(nxt + dstOff[l]), 16, 0, 0);
        }

        // 3. fragment reads (swizzled, conflict-free): one b128 = one K=64 i8 fragment
        i32x4 aF[4], bF[4];
#pragma unroll
        for (int mi = 0; mi < 4; ++mi) {
            const int r = wr * 64 + mi * 16 + (lane & 15);
            const int phys = fc ^ ((r >> 1) & 3);
            aF[mi] = *(const i32x4*)(cur + r * 64 + phys * 16);
        }
#pragma unroll
        for (int ni = 0; ni < 4; ++ni) {
            const int r = wc * 64 + ni * 16 + (lane & 15);
            const int phys = fc ^ ((r >> 1) & 3);
            bF[ni] = *(const i32x4*)(cur + 16384 + r * 64 + phys * 16);
        }

        __builtin_amdgcn_s_setprio(1);
#pragma unroll
        for (int mi = 0; mi < 4; ++mi)
#pragma unroll
            for (int ni = 0; ni < 4; ++ni)
                acc[mi][ni] = __builtin_amdgcn_mfma_i32_16x16x64_i8(
                    aF[mi], bF[ni], acc[mi][ni], 0, 0, 0);
        __builtin_amdgcn_s_setprio(0);

        // 4. counted fence. Non-xt iters: vmcnt(3) -- all but tile t+2's 3 gloads
        // land (tile t+1 staged; any xt loads from iter t-? also forced, with
        // >=1.3 iters of age). xt iters: vmcnt(6) -- the <=6 VMEM ops issued THIS
        // iter (store + 3 gloads + 2 loads) are all newer than tile t+1's gloads
        // regardless of intra-iteration issue order, so "t+1 landed" still holds.
        if (t + 2 < NKT) {
            if (xt_iter)
                asm volatile("s_waitcnt vmcnt(6)" ::: "memory");
            else
                asm volatile("s_waitcnt vmcnt(3)" ::: "memory");
        } else {
            asm volatile("s_waitcnt vmcnt(0)" ::: "memory");
        }
        asm volatile("s_barrier" ::: "memory");
    }

    // drain x_t pipeline: final slice
    if (iP >= 0) {
        float4 o;
        o.x = fmaf(sc, vbP.x, vaP.x);
        o.y = fmaf(sc, vbP.y, vaP.y);
        o.z = fmaf(sc, vbP.z, vaP.z);
        o.w = fmaf(sc, vbP.w, vaP.w);
        xt4[iP] = o;
    }

    // ---- fused epilogue: exp terms + row/col partial sums ----
    const float var = __expf(lv) + 1e-10f;
    const float cc  = 0.5f / var;

    const int u = 2 * a + (wr >> 1);        // this wave's 128-row cell index
    if (u > v) return;                      // below-diagonal half of a v==2a tile

    const int colBase = (int)rowB0 + wc * 64 + (lane & 15);
    const int rowBase = (int)rowA0 + wr * 64 + (lane >> 4) * 4;

    // row sums -> se[i]  (i==j override handles diagonal cells exactly)
#pragma unroll
    for (int mi = 0; mi < 4; ++mi) {
#pragma unroll
        for (int rg = 0; rg < 4; ++rg) {
            const int i = rowBase + mi * 16 + rg;
            const float xni = xn[i];
            float rs = 0.f;
#pragma unroll
            for (int ni = 0; ni < 4; ++ni) {
                const int j = colBase + ni * 16;
                const float g = (float)acc[mi][ni][rg] * INV_S2;
                const float dist = xni + xn[j] - 2.f * g;
                rs += (i == j) ? 1.0f : __expf(-cc * fmaxf(dist, 0.f));
            }
#pragma unroll
            for (int d = 1; d < 16; d <<= 1) rs += __shfl_xor(rs, d);
            if ((lane & 15) == 0) atomicAdd(&se[i], rs);
        }
    }

    // col-mirror sums -> se[j], strictly-off-diagonal cells only (i < j always)
    if (u < v) {
#pragma unroll
        for (int ni = 0; ni < 4; ++ni) {
            const int j = colBase + ni * 16;
            const float xnj = xn[j];
            float cs = 0.f;
#pragma unroll
            for (int mi = 0; mi < 4; ++mi)
#pragma unroll
                for (int rg = 0; rg < 4; ++rg) {
                    const int i = rowBase + mi * 16 + rg;
                    const float g = (float)acc[mi][ni][rg] * INV_S2;
                    cs += __expf(-cc * fmaxf(xn[i] + xnj - 2.f * g, 0.f));
                }
#pragma unroll
            for (int d = 16; d < 64; d <<= 1) cs += __shfl_xor(cs, d);
            if ((lane >> 4) == 0) atomicAdd(&se[j], cs);
        }
    }
}

// ---------- kernel 3: KL scalar ----------
__global__ __launch_bounds__(256) void kl_kernel(const float* __restrict__ se,
                                                 float* __restrict__ out)
{
    const int tid = threadIdx.x;
    float s = 0.f;
    for (int i = tid; i < B_DIM; i += 256) s += logf(se[i]);
#pragma unroll
    for (int d = 32; d > 0; d >>= 1) s += __shfl_down(s, d);
    __shared__ float red[4];
    if ((tid & 63) == 0) red[tid >> 6] = s;
    __syncthreads();
    if (tid == 0) {
        const float dc = -(red[0] + red[1] + red[2] + red[3]) / (float)B_DIM;
        out[0] = (logf((float)B_DIM) + dc) / logf(2.f);
    }
}

// ---------- kernel 4 (fallback path only): x_t elementwise ----------
__global__ __launch_bounds__(256) void xt_kernel(const float4* __restrict__ x,
                                                 const float4* __restrict__ nz,
                                                 const float* __restrict__ logvar,
                                                 float4* __restrict__ out, int n4)
{
    const float sc = expf(0.5f * logvar[0]);
    for (int i = blockIdx.x * blockDim.x + threadIdx.x; i < n4;
         i += gridDim.x * blockDim.x) {
        float4 va = x[i], vb = nz[i];
        float4 o;
        o.x = fmaf(sc, vb.x, va.x);
        o.y = fmaf(sc, vb.y, va.y);
        o.z = fmaf(sc, vb.z, va.z);
        o.w = fmaf(sc, vb.w, va.w);
        out[i] = o;
    }
}

extern "C" void kernel_launch(void* const* d_in, const int* in_sizes, int n_in,
                              void* d_out, int out_size, void* d_ws, size_t ws_size,
                              hipStream_t stream)
{
    const float* x      = (const float*)d_in[0];
    const float* noise  = (const float*)d_in[1];
    const float* logvar = (const float*)d_in[2];
    float* out = (float*)d_out;

    const size_t NEL      = (size_t)B_DIM * K_DIM;      // 25165824
    const size_t XB_BYTES = (size_t)B_DIM * ROW_B;      // 25165824 B

    const bool use_ws = ws_size >= XB_BYTES + 2 * (size_t)B_DIM * sizeof(float) + 256;

    if (use_ws) {
        // xb/xn/se live in d_ws; x_t streamed from inside gram's K-loop
        unsigned int* xb = (unsigned int*)d_ws;
        float* xn = (float*)((char*)d_ws + XB_BYTES);
        float* se = xn + B_DIM;

        prep_kernel<<<B_DIM, 384, 0, stream>>>(x, xb, xn, se);
        gram_lse_kernel<<<NTILES, 512, 0, stream>>>(xb, xn, logvar, se,
                                                    (const float4*)x,
                                                    (const float4*)noise,
                                                    (float4*)out);
        kl_kernel<<<1, 256, 0, stream>>>(se, out + NEL);
    } else {
        // fallback: scratch carved from d_out; x_t must wait until gram is done
        unsigned int* xb = (unsigned int*)d_out;
        float* xn = (float*)((char*)d_out + (32u << 20));
        float* se = xn + B_DIM;

        prep_kernel<<<B_DIM, 384, 0, stream>>>(x, xb, xn, se);
        gram_lse_kernel<<<NTILES, 512, 0, stream>>>(xb, xn, logvar, se,
                                                    (const float4*)x,
                                                    (const float4*)noise,
                                                    nullptr);
        kl_kernel<<<1, 256, 0, stream>>>(se, out + NEL);
        xt_kernel<<<2048, 256, 0, stream>>>((const float4*)x, (const float4*)noise,
                                            logvar, (float4*)out, (int)(NEL / 4));
    }
}